// Round 9
// baseline (299.563 us; speedup 1.0000x reference)
//
#include <hip/hip_runtime.h>
#include <hip/hip_fp16.h>

// Problem constants
#define N_NODES 100000
#define N_EDGES 3200000
#define IN_F    128
#define HID     3
#define OUT_F   4

// dest-stripe partition: 256 dests per stripe
#define DBITS   8
#define DTILE   256
#define DMASK   255
#define NSTRIPE 391                                  // ceil(100000/256)
#define MAXE    12288                                // mean 8184, +45 sigma headroom
#define MAXIT   24                                   // MAXE/512

// pass-1 partition
#define NBLKA   1024
#define THRA    256
#define EPB     ((N_EDGES + NBLKA - 1) / NBLKA)      // 3125
#define N1      (NSTRIPE * NBLKA)                    // 400384

#define SCAN_ITEMS 16
#define SCAN_BLOCK 256
#define SCAN_PER_BLOCK (SCAN_ITEMS * SCAN_BLOCK)     // 4096
#define NS1 ((N1 + SCAN_PER_BLOCK - 1) / SCAN_PER_BLOCK)  // 98

typedef float f32x4 __attribute__((ext_vector_type(4)));

// ---------------- xw = x @ W ---------------------------------------------
__global__ void xw_kernel(const float* __restrict__ x,
                          const float* __restrict__ W,
                          float* __restrict__ xw) {
    int wave = threadIdx.x >> 6;
    int lane = threadIdx.x & 63;
    int half = lane >> 5;
    int l    = lane & 31;
    int node = blockIdx.x * 8 + wave * 2 + half;
    if (node >= N_NODES) return;
    f32x4 xv = __builtin_nontemporal_load(
        reinterpret_cast<const f32x4*>(x + (size_t)node * IN_F + l * 4));
    const float* w = W + l * 4 * HID;
    float s0 = xv.x * w[0] + xv.y * w[3] + xv.z * w[6] + xv.w * w[9];
    float s1 = xv.x * w[1] + xv.y * w[4] + xv.z * w[7] + xv.w * w[10];
    float s2 = xv.x * w[2] + xv.y * w[5] + xv.z * w[8] + xv.w * w[11];
    #pragma unroll
    for (int off = 16; off > 0; off >>= 1) {
        s0 += __shfl_down(s0, off, 32);
        s1 += __shfl_down(s1, off, 32);
        s2 += __shfl_down(s2, off, 32);
    }
    if (l == 0) {
        xw[node * 3 + 0] = s0;
        xw[node * 3 + 1] = s1;
        xw[node * 3 + 2] = s2;
    }
}

// ---------- hist1: per-block histogram over 391 dst-stripes --------------
__global__ __launch_bounds__(THRA) void hist1_kernel(const int* __restrict__ col,
                                                     int* __restrict__ histG) {
    __shared__ int hist[8 * NSTRIPE];
    int tid = threadIdx.x, blk = blockIdx.x;
    for (int i = tid; i < 8 * NSTRIPE; i += THRA) hist[i] = 0;
    __syncthreads();
    int start = blk * EPB, end = min(start + EPB, N_EDGES);
    for (int e = start + tid; e < end; e += THRA)
        atomicAdd(&hist[(tid & 7) * NSTRIPE +
                        (__builtin_nontemporal_load(&col[e]) >> DBITS)], 1);
    __syncthreads();
    for (int s = tid; s < NSTRIPE; s += THRA) {
        int v = 0;
        #pragma unroll
        for (int r = 0; r < 8; ++r) v += hist[r * NSTRIPE + s];
        histG[s * NBLKA + blk] = v;
    }
}

// ---------------- exclusive scan over histG[N1] --------------------------
__global__ void scan1_kernel(int* __restrict__ data, int* __restrict__ bsum) {
    __shared__ int s[SCAN_BLOCK];
    int tid = threadIdx.x;
    int base = blockIdx.x * SCAN_PER_BLOCK + tid * SCAN_ITEMS;
    int v[SCAN_ITEMS];
    int tsum = 0;
    #pragma unroll
    for (int j = 0; j < SCAN_ITEMS; ++j) {
        v[j] = (base + j < N1) ? data[base + j] : 0;
        tsum += v[j];
    }
    s[tid] = tsum;
    __syncthreads();
    for (int off = 1; off < SCAN_BLOCK; off <<= 1) {
        int t = (tid >= off) ? s[tid - off] : 0;
        __syncthreads();
        s[tid] += t;
        __syncthreads();
    }
    int run = s[tid] - tsum;
    #pragma unroll
    for (int j = 0; j < SCAN_ITEMS; ++j) {
        int t = v[j];
        if (base + j < N1) data[base + j] = run;
        run += t;
    }
    if (tid == SCAN_BLOCK - 1) bsum[blockIdx.x] = s[SCAN_BLOCK - 1];
}

__global__ void scan2_kernel(int* __restrict__ bsum) {
    __shared__ int s[SCAN_BLOCK];
    int tid = threadIdx.x;
    int v = (tid < NS1) ? bsum[tid] : 0;
    s[tid] = v;
    __syncthreads();
    for (int off = 1; off < SCAN_BLOCK; off <<= 1) {
        int t = (tid >= off) ? s[tid - off] : 0;
        __syncthreads();
        s[tid] += t;
        __syncthreads();
    }
    if (tid < NS1) bsum[tid] = s[tid] - v;
}

__global__ void scan3_kernel(int* __restrict__ data, const int* __restrict__ bsum) {
    int i = blockIdx.x * blockDim.x + threadIdx.x;
    if (i < N1) data[i] += bsum[i / SCAN_PER_BLOCK];
}

// ---------- fill1: scatter packed1 = (src<<8 | dst&255) by stripe --------
__global__ __launch_bounds__(THRA) void fill1_kernel(const int* __restrict__ row,
                                                     const int* __restrict__ col,
                                                     const int* __restrict__ histG,
                                                     int* __restrict__ packed1) {
    __shared__ int offs[NSTRIPE];
    int tid = threadIdx.x, blk = blockIdx.x;
    for (int i = tid; i < NSTRIPE; i += THRA) offs[i] = histG[i * NBLKA + blk];
    __syncthreads();
    int start = blk * EPB, end = min(start + EPB, N_EDGES);
    for (int e = start + tid; e < end; e += THRA) {
        int c = __builtin_nontemporal_load(&col[e]);
        int r = __builtin_nontemporal_load(&row[e]);
        int s = c >> DBITS;
        int pos = atomicAdd(&offs[s], 1);       // the ONLY per-edge atomic
        packed1[pos] = (r << DBITS) | (c & DMASK);
    }
}

// ---------- sortA: per-stripe ballot-radix sort (NO atomics) -------------
// Sorts the stripe's edges by low-8-bit dest, builds CSR offsets via binary
// search, computes per-dest degree -> fp16 tab, writes sorted src list.
__global__ __launch_bounds__(512, 1) void sortA_kernel(const int* __restrict__ histG,
                                                       const int* __restrict__ packed1,
                                                       const float* __restrict__ xw,
                                                       uint2* __restrict__ tab,
                                                       int* __restrict__ csrOff,
                                                       int* __restrict__ srcSorted) {
    __shared__ int ping[MAXE];
    __shared__ int pong[MAXE];
    __shared__ int cntW[4 * MAXIT * 8];
    __shared__ int bounds[DTILE + 1];
    int tid = threadIdx.x, s = blockIdx.x;
    int lane = tid & 63, wv = tid >> 6;
    unsigned long long ltmask = (lane == 63) ? ~0ULL >> 1
                                             : (1ULL << lane) - 1;

    int seg0 = histG[s * NBLKA];
    int seg1 = (s + 1 < NSTRIPE) ? histG[(s + 1) * NBLKA] : N_EDGES;
    int len = min(seg1 - seg0, MAXE);
    int nIter = (len + 511) >> 9;

    for (int i = tid; i < len; i += 512)
        ping[i] = __builtin_nontemporal_load(&packed1[seg0 + i]);
    __syncthreads();

    int* srcb = ping;
    int* dstb = pong;
    for (int shift = 0; shift < DBITS; shift += 2) {
        // phase 1: per-(iter,wave) bucket counts via ballot
        for (int it = 0; it < nIter; ++it) {
            int idx = it * 512 + tid;
            int bk = (idx < len) ? ((srcb[idx] >> shift) & 3) : -1;
            unsigned long long m0 = __ballot(bk == 0);
            unsigned long long m1 = __ballot(bk == 1);
            unsigned long long m2 = __ballot(bk == 2);
            unsigned long long m3 = __ballot(bk == 3);
            if (lane == 0) {
                cntW[(0 * nIter + it) * 8 + wv] = __popcll(m0);
                cntW[(1 * nIter + it) * 8 + wv] = __popcll(m1);
                cntW[(2 * nIter + it) * 8 + wv] = __popcll(m2);
                cntW[(3 * nIter + it) * 8 + wv] = __popcll(m3);
            }
        }
        __syncthreads();
        // phase 2: exclusive scan of cntW[4*nIter*8] by wave 0
        if (wv == 0) {
            int n = 4 * nIter * 8;
            int carry = 0;
            int nch = (n + 63) >> 6;
            for (int c = 0; c < nch; ++c) {
                int i = c * 64 + lane;
                int v = (i < n) ? cntW[i] : 0;
                int x = v;
                #pragma unroll
                for (int o = 1; o < 64; o <<= 1) {
                    int t = __shfl_up(x, o, 64);
                    if (lane >= o) x += t;
                }
                if (i < n) cntW[i] = carry + x - v;
                carry += __shfl(x, 63, 64);
            }
        }
        __syncthreads();
        // phase 3: rank + scatter (stable: bucket-major, iter, wave, lane)
        for (int it = 0; it < nIter; ++it) {
            int idx = it * 512 + tid;
            int p = (idx < len) ? srcb[idx] : 0;
            int bk = (idx < len) ? ((p >> shift) & 3) : -1;
            unsigned long long m0 = __ballot(bk == 0);
            unsigned long long m1 = __ballot(bk == 1);
            unsigned long long m2 = __ballot(bk == 2);
            unsigned long long m3 = __ballot(bk == 3);
            if (idx < len) {
                unsigned long long mk = (bk == 0) ? m0 : (bk == 1) ? m1
                                      : (bk == 2) ? m2 : m3;
                int base = cntW[(bk * nIter + it) * 8 + wv];
                int rank = __popcll(mk & ltmask);
                dstb[base + rank] = p;
            }
        }
        __syncthreads();
        int* t = srcb; srcb = dstb; dstb = t;
    }
    // data back in ping (4 swaps). CSR boundaries via binary search.
    if (tid <= DTILE) {
        int target = tid;
        int lo = 0, hi = len;
        while (lo < hi) {
            int mid = (lo + hi) >> 1;
            if ((ping[mid] & DMASK) < target) lo = mid + 1; else hi = mid;
        }
        bounds[tid] = lo;
    }
    __syncthreads();
    int nodeBase = s * DTILE;
    if (tid <= DTILE) {
        int node = nodeBase + tid;
        if (node <= N_NODES) csrOff[node] = seg0 + bounds[tid];
    }
    if (tid < DTILE) {
        int node = nodeBase + tid;
        if (node < N_NODES) {
            int deg = bounds[tid + 1] - bounds[tid];
            float d = rsqrtf((float)(deg + 1));   // +1 self loop
            __half2 lo2 = __floats2half2_rn(xw[node * 3 + 0] * d, xw[node * 3 + 1] * d);
            __half2 hi2 = __floats2half2_rn(xw[node * 3 + 2] * d, d);
            uint2 u;
            u.x = *reinterpret_cast<unsigned int*>(&lo2);
            u.y = *reinterpret_cast<unsigned int*>(&hi2);
            tab[node] = u;
        }
    }
    for (int i = tid; i < len; i += 512)
        srcSorted[seg0 + i] = ping[i] >> DBITS;
}

// ---------- reduceB: 4 threads per dest, atomic-free gather-reduce -------
__global__ __launch_bounds__(512) void reduceB_kernel(const int* __restrict__ csrOff,
                                                      const int* __restrict__ srcSorted,
                                                      const uint2* __restrict__ tab,
                                                      const float* __restrict__ bb,
                                                      const float* __restrict__ Wout,
                                                      const float* __restrict__ bout,
                                                      float* __restrict__ out) {
    int gid = blockIdx.x * 512 + threadIdx.x;
    int dest = gid >> 2, sub = gid & 3;
    if (dest >= N_NODES) return;
    int start = csrOff[dest], end = csrOff[dest + 1];
    float a0 = 0.f, a1 = 0.f, a2 = 0.f;
    for (int i = start + sub; i < end; i += 4) {
        int r = srcSorted[i];
        uint2 u = tab[r];
        __half2 lo = *reinterpret_cast<__half2*>(&u.x);
        __half2 hi = *reinterpret_cast<__half2*>(&u.y);
        float2 f0 = __half22float2(lo);
        float2 f1 = __half22float2(hi);
        a0 += f0.x; a1 += f0.y; a2 += f1.x;
    }
    // combine the 4-lane group (lanes 4k..4k+3 share a dest)
    a0 += __shfl_down(a0, 2, 64); a1 += __shfl_down(a1, 2, 64); a2 += __shfl_down(a2, 2, 64);
    a0 += __shfl_down(a0, 1, 64); a1 += __shfl_down(a1, 1, 64); a2 += __shfl_down(a2, 1, 64);
    if (sub == 0) {
        uint2 u = tab[dest];
        __half2 lo = *reinterpret_cast<__half2*>(&u.x);
        __half2 hi = *reinterpret_cast<__half2*>(&u.y);
        float2 f0 = __half22float2(lo);
        float2 f1 = __half22float2(hi);
        float di = f1.y;
        float h0 = fmaxf((a0 + f0.x) * di + bb[0], 0.f);
        float h1 = fmaxf((a1 + f0.y) * di + bb[1], 0.f);
        float h2 = fmaxf((a2 + f1.x) * di + bb[2], 0.f);
        out[dest * 3 + 0] = h0;
        out[dest * 3 + 1] = h1;
        out[dest * 3 + 2] = h2;
        float* z = out + (size_t)N_NODES * 3;
        #pragma unroll
        for (int k = 0; k < 4; ++k) {
            z[dest * 4 + k] = bout[k] + h0 * Wout[0 * 4 + k]
                                      + h1 * Wout[1 * 4 + k]
                                      + h2 * Wout[2 * 4 + k];
        }
    }
}

static inline size_t align256(size_t x) { return (x + 255) & ~(size_t)255; }

extern "C" void kernel_launch(void* const* d_in, const int* in_sizes, int n_in,
                              void* d_out, int out_size, void* d_ws, size_t ws_size,
                              hipStream_t stream) {
    const float* x    = (const float*)d_in[0];
    const int*   ei   = (const int*)d_in[1];
    const float* W    = (const float*)d_in[2];
    const float* b    = (const float*)d_in[3];
    const float* Wout = (const float*)d_in[4];
    const float* bout = (const float*)d_in[5];
    float* out = (float*)d_out;

    char* wsb = (char*)d_ws;
    size_t off = 0;
    int*   histG     = (int*)(wsb + off);  off = align256(off + (size_t)N1 * 4);
    int*   packed1   = (int*)(wsb + off);  off = align256(off + (size_t)N_EDGES * 4);
    int*   srcSorted = (int*)(wsb + off);  off = align256(off + (size_t)N_EDGES * 4);
    float* xw        = (float*)(wsb + off); off = align256(off + (size_t)N_NODES * 3 * 4);
    uint2* tab       = (uint2*)(wsb + off); off = align256(off + (size_t)N_NODES * 8);
    int*   csrOff    = (int*)(wsb + off);  off = align256(off + ((size_t)N_NODES + 1) * 4);
    int*   bsum      = (int*)(wsb + off);  off = align256(off + (size_t)NS1 * 4);

    const int* row = ei;
    const int* col = ei + N_EDGES;

    xw_kernel<<<(N_NODES + 7) / 8, 256, 0, stream>>>(x, W, xw);
    hist1_kernel<<<NBLKA, THRA, 0, stream>>>(col, histG);
    scan1_kernel<<<NS1, SCAN_BLOCK, 0, stream>>>(histG, bsum);
    scan2_kernel<<<1, SCAN_BLOCK, 0, stream>>>(bsum);
    scan3_kernel<<<(N1 + 255) / 256, 256, 0, stream>>>(histG, bsum);
    fill1_kernel<<<NBLKA, THRA, 0, stream>>>(row, col, histG, packed1);
    sortA_kernel<<<NSTRIPE, 512, 0, stream>>>(histG, packed1, xw, tab, csrOff, srcSorted);
    reduceB_kernel<<<(N_NODES * 4 + 511) / 512, 512, 0, stream>>>(csrOff, srcSorted, tab,
                                                                  b, Wout, bout, out);
}